// Round 14
// baseline (236.164 us; speedup 1.0000x reference)
//
#include <hip/hip_runtime.h>
#include <math.h>

typedef int intx4 __attribute__((ext_vector_type(4)));
typedef int intx8 __attribute__((ext_vector_type(8)));
typedef float floatx16 __attribute__((ext_vector_type(16)));

#define N_ROWS 8192
#define KDIM 1024

// E8M0 scale bytes: 123 -> 2^-4 per side (data pre-scaled by 2^4 each side)
#define SCALE_WORD 0x7B7B7B7B

// order-preserving float->int encoding for atomicMax
__device__ __forceinline__ int fenc(float f) {
  int i = __float_as_int(f);
  return i >= 0 ? i : (i ^ 0x7fffffff);
}
__device__ __forceinline__ float fdec(int e) {
  int b = e >= 0 ? e : (e ^ 0x7fffffff);
  return __int_as_float(b);
}

// One WAVE per row (4 rows/block): computes 1/||x|| (fp32), writes the row
// as e4m3 (*16 pre-scale) via HW cvt, inits the max slot.
//  - ex side: written PRE-PACKED in 32x32x64 A-operand fragment layout:
//      byte k of row r  ->  exn[(g*16 + c)*2048 + (h*32 + l32)*32 + b]
//    where g=r>>5, l32=r&31, c=k>>6, h=(k>>5)&1, b=k&31. A gemm wave then
//    loads its fragment as ONE coalesced 2 KB block (lane*32), no LDS.
//  - ey side: row-major as before (B goes through the verified LDS path).
__global__ __launch_bounds__(256) void normalize_kernel(
    const float* __restrict__ ex, const float* __restrict__ ey,
    unsigned char* __restrict__ exn, unsigned char* __restrict__ eyn,
    int* __restrict__ rowmax, int* __restrict__ colmax) {
  const int wave = threadIdx.x >> 6, lane = threadIdx.x & 63;
  const int gr = blockIdx.x * 4 + wave;  // 0..16383
  const float* x;
  int* mslot;
  int row;
  if (gr < N_ROWS) {
    x = ex; mslot = rowmax; row = gr;
  } else {
    x = ey; mslot = colmax; row = gr - N_ROWS;
  }
  const float4* xr = (const float4*)(x + (size_t)row * KDIM);
  float4 v[4];
  float ss = 0.f;
#pragma unroll
  for (int j = 0; j < 4; ++j) {
    v[j] = xr[lane + j * 64];  // coalesced
    ss += v[j].x * v[j].x + v[j].y * v[j].y + v[j].z * v[j].z + v[j].w * v[j].w;
  }
#pragma unroll
  for (int off = 32; off > 0; off >>= 1) ss += __shfl_xor(ss, off, 64);
  const float rs = 16.0f * rsqrtf(fmaxf(ss, 1e-24f));  // 2^4 pre-scale
  if (gr < N_ROWS) {
    const int g = row >> 5, l32r = row & 31;
#pragma unroll
    for (int j = 0; j < 4; ++j) {
      int w = __builtin_amdgcn_cvt_pk_fp8_f32(v[j].x * rs, v[j].y * rs, 0, false);
      w = __builtin_amdgcn_cvt_pk_fp8_f32(v[j].z * rs, v[j].w * rs, w, true);
      const int k4 = (lane + j * 64) * 4;
      const int c = k4 >> 6, h = (k4 >> 5) & 1, b = k4 & 31;
      *(int*)(exn + (size_t)(g * 16 + c) * 2048 + (h * 32 + l32r) * 32 + b) = w;
    }
  } else {
    int* op = (int*)(eyn + (size_t)row * KDIM);
#pragma unroll
    for (int j = 0; j < 4; ++j) {
      int w = __builtin_amdgcn_cvt_pk_fp8_f32(v[j].x * rs, v[j].y * rs, 0, false);
      w = __builtin_amdgcn_cvt_pk_fp8_f32(v[j].z * rs, v[j].w * rs, w, true);
      op[lane + j * 64] = w;
    }
  }
  if (lane == 0) mslot[row] = (int)0x80000000;  // encoded -inf floor
}

// 128x128 tile GEMM (C = A @ B^T) with mfma_scale_f32_32x32x64_f8f6f4,
// fused row/col max reduction.
//
// Round-14 change: A-operand DIRECT FROM GLOBAL (pre-packed fragment layout,
// see normalize) — A never touches LDS. Per-block-step LDS traffic halves
// (48 -> 24 KB: B write 8 + B reads 16), A's ds_read latency leaves the
// critical path, and A-fragment loads are coalesced 2 KB/wave prefetched one
// phase ahead into operand registers (ping-pong aC/aN, no copies).
// Grid is bn-fast (bm = blockIdx.y) so the 64 blocks sharing an A row-slice
// are co-resident: 128 KB hot A set per XCD L2.
//
// B pipeline (verified r6-r13): buffer_load->VGPR->ds_write; only vmcnt
// wait is the ds_write data dependence, placed AFTER compute.
// B LDS swizzle (verified r8+): chunk c of row r at slot c ^ ((r>>1)&3);
// staging source chunk (lane&3)^((lane>>3)&3), fragment slots oLo/oHi.
// Operand content at (lane, byte) is identical for A and B paths ->
// dot-product pairing exact (absmax 0.0 through r13).
__global__ __launch_bounds__(256, 4) void gemm_max_kernel(
    const unsigned char* __restrict__ Apk, const unsigned char* __restrict__ B,
    int* __restrict__ rowmax, int* __restrict__ colmax) {
  constexpr int TM = 128, BK = 64, K = KDIM;
  constexpr int BUFB = TM * BK;                          // 8 KB per buffer
  __shared__ __align__(16) unsigned char sB[2 * BUFB];   // 16 KB total

  const int bn = blockIdx.x, bm = blockIdx.y;  // bn-fast for A reuse
  const int tid = threadIdx.x;
  const int lane = tid & 63, wave = tid >> 6;
  const int wm = wave >> 1, wn = wave & 1;  // 2x2 waves of 64x64
  const int l32 = lane & 31, half = lane >> 5;
  const int fsw = (l32 >> 1) & 3;                 // f(row) = (row>>1)&3
  const int oLo = (((2 * half + 0) ^ fsw) << 4);  // swizzled slot offsets
  const int oHi = (((2 * half + 1) ^ fsw) << 4);

  floatx16 acc[2][2] = {};

  // B staging: wave w stages rows w*32..+31 per step (2 chunks/lane).
  const int src_c16 = (((lane & 3) ^ ((lane >> 3) & 3)) << 4);
  const char* gB = (const char*)B +
                   (size_t)(bm * 0 + bn * TM + wave * 32 + (lane >> 2)) * K +
                   src_c16;
  unsigned char* wB = sB + wave * 2048 + lane * 16;

  // A packed base for this wave: rowgroups g0 = bm*4 + wm*2 (+mi).
  const char* pA = (const char*)Apk +
                   (size_t)(bm * 4 + wm * 2) * 16 * 2048 + lane * 32;

  intx4 pf[2];        // B prefetch: 2 chunks (8 VGPRs)
  intx8 aC[2], aN[2]; // A operand ping-pong (32 VGPRs)

#define LOADB(stp)                                                \
  do {                                                            \
    pf[0] = *(const intx4*)(gB + (size_t)(stp)*BK);               \
    pf[1] = *(const intx4*)(gB + (size_t)(stp)*BK + 16 * K);      \
  } while (0)

#define WRITEB(buf)                                               \
  do {                                                            \
    *(intx4*)(wB + (buf)*BUFB) = pf[0];                           \
    *(intx4*)(wB + (buf)*BUFB + 1024) = pf[1];                    \
  } while (0)

#define LOADA(dst, stp)                                           \
  do {                                                            \
    dst[0] = *(const intx8*)(pA + (size_t)(stp)*2048);            \
    dst[1] = *(const intx8*)(pA + 32768 + (size_t)(stp)*2048);    \
  } while (0)

#define COMPUTE(cur, aR)                                                    \
  do {                                                                      \
    _Pragma("unroll") for (int ni = 0; ni < 2; ++ni) {                      \
      const unsigned char* bBase =                                          \
          &sB[(cur)*BUFB + (wn * 64 + ni * 32 + l32) * BK];                 \
      const intx4 lo = *(const intx4*)(bBase + oLo);                        \
      const intx4 hi = *(const intx4*)(bBase + oHi);                        \
      const intx8 bF =                                                      \
          __builtin_shufflevector(lo, hi, 0, 1, 2, 3, 4, 5, 6, 7);          \
      _Pragma("unroll") for (int mi = 0; mi < 2; ++mi)                      \
          acc[mi][ni] = __builtin_amdgcn_mfma_scale_f32_32x32x64_f8f6f4(    \
              aR[mi], bF, acc[mi][ni], 0, 0, 0, SCALE_WORD, 0,              \
              SCALE_WORD);                                                  \
    }                                                                       \
  } while (0)

  LOADB(0);
  LOADA(aC, 0);
  WRITEB(0);
  __syncthreads();

  // Paired steps: register ping-pong for A (no copies), one barrier/step.
#pragma unroll 1
  for (int s = 0; s < 14; s += 2) {
    LOADB(s + 1);
    LOADA(aN, s + 1);
    COMPUTE(0, aC);
    WRITEB(1);
    __syncthreads();
    LOADB(s + 2);
    LOADA(aC, s + 2);
    COMPUTE(1, aN);
    WRITEB(0);
    __syncthreads();
  }
  // tail: steps 14, 15
  LOADB(15);
  LOADA(aN, 15);
  COMPUTE(0, aC);
  WRITEB(1);
  __syncthreads();
  COMPUTE(1, aN);

#undef LOADB
#undef WRITEB
#undef LOADA
#undef COMPUTE

  // 32x32 C/D layout (m74/m101, dtype-independent):
  //   col = lane&31, row = (reg&3) + 8*(reg>>2) + 4*(lane>>5), reg in [0,16)
#pragma unroll
  for (int mi = 0; mi < 2; ++mi) {
#pragma unroll
    for (int reg = 0; reg < 16; ++reg) {
      float v = fmaxf(acc[mi][0][reg], acc[mi][1][reg]);
#pragma unroll
      for (int m = 1; m < 32; m <<= 1) v = fmaxf(v, __shfl_xor(v, m, 64));
      if (l32 == 0) {
        const int grow = bm * TM + wm * 64 + mi * 32 +
                         (reg & 3) + 8 * (reg >> 2) + 4 * half;
        atomicMax(&rowmax[grow], fenc(v));
      }
    }
  }
#pragma unroll
  for (int ni = 0; ni < 2; ++ni) {
    float v = -3.402823466e38f;
#pragma unroll
    for (int mi = 0; mi < 2; ++mi)
#pragma unroll
      for (int reg = 0; reg < 16; ++reg) v = fmaxf(v, acc[mi][ni][reg]);
    v = fmaxf(v, __shfl_xor(v, 32, 64));
    if (half == 0) {
      const int gcol = bn * TM + wn * 64 + ni * 32 + l32;
      atomicMax(&colmax[gcol], fenc(v));
    }
  }
}

__global__ __launch_bounds__(1024) void finalize_kernel(
    const int* __restrict__ rowmax, const int* __restrict__ colmax,
    float* __restrict__ out) {
  const int tid = threadIdx.x;
  float s1 = 0.f, s2 = 0.f;
  for (int i = tid; i < N_ROWS; i += 1024) {
    s1 += 1.0f - fdec(rowmax[i]);
    s2 += 1.0f - fdec(colmax[i]);
  }
#pragma unroll
  for (int off = 32; off > 0; off >>= 1) {
    s1 += __shfl_down(s1, off, 64);
    s2 += __shfl_down(s2, off, 64);
  }
  __shared__ float r1[16], r2[16];
  if ((tid & 63) == 0) {
    r1[tid >> 6] = s1;
    r2[tid >> 6] = s2;
  }
  __syncthreads();
  if (tid == 0) {
    const double SIGMA = 0.3;
    const double H_CONST = 0.5 * log(2.0 * 3.14159265358979323846 * SIGMA * SIGMA) + 0.5;
    const float HS = (float)(H_CONST / SIGMA);
    float a1 = 0.f, a2 = 0.f;
#pragma unroll
    for (int w = 0; w < 16; ++w) {
      a1 += r1[w];
      a2 += r2[w];
    }
    out[0] = HS * a1;
    out[1] = HS * a2;
  }
}

extern "C" void kernel_launch(void* const* d_in, const int* in_sizes, int n_in,
                              void* d_out, int out_size, void* d_ws, size_t ws_size,
                              hipStream_t stream) {
  const float* ex = (const float*)d_in[0];
  const float* ey = (const float*)d_in[1];
  float* out = (float*)d_out;
  char* ws = (char*)d_ws;

  unsigned char* exn = (unsigned char*)ws;                                   // 8 MB (packed A)
  unsigned char* eyn = (unsigned char*)(ws + (size_t)N_ROWS * KDIM);         // 8 MB (row-major B)
  int* rowmax = (int*)(ws + (size_t)N_ROWS * KDIM * 2);                      // 32 KB
  int* colmax = rowmax + N_ROWS;                                             // 32 KB

  normalize_kernel<<<2 * N_ROWS / 4, 256, 0, stream>>>(ex, ey, exn, eyn,
                                                       rowmax, colmax);
  gemm_max_kernel<<<dim3(64, 64), 256, 0, stream>>>(exn, eyn, rowmax, colmax);
  finalize_kernel<<<1, 1024, 0, stream>>>(rowmax, colmax, out);
}

// Round 15
// 204.245 us; speedup vs baseline: 1.1563x; 1.1563x over previous
//
#include <hip/hip_runtime.h>
#include <math.h>

typedef int intx4 __attribute__((ext_vector_type(4)));
typedef int intx8 __attribute__((ext_vector_type(8)));
typedef float floatx16 __attribute__((ext_vector_type(16)));

#define N_ROWS 8192
#define KDIM 1024

// E8M0 scale bytes: 123 -> 2^-4 per side (data pre-scaled by 2^4 each side)
#define SCALE_WORD 0x7B7B7B7B

// order-preserving float->int encoding for atomicMax
__device__ __forceinline__ int fenc(float f) {
  int i = __float_as_int(f);
  return i >= 0 ? i : (i ^ 0x7fffffff);
}
__device__ __forceinline__ float fdec(int e) {
  int b = e >= 0 ? e : (e ^ 0x7fffffff);
  return __int_as_float(b);
}

// One WAVE per row (4 rows/block, no __syncthreads): computes 1/||x|| (fp32),
// writes row normalized*16 as e4m3 via HW cvt, inits the max slot.
__global__ __launch_bounds__(256) void normalize_kernel(
    const float* __restrict__ ex, const float* __restrict__ ey,
    unsigned char* __restrict__ exn, unsigned char* __restrict__ eyn,
    int* __restrict__ rowmax, int* __restrict__ colmax) {
  const int wave = threadIdx.x >> 6, lane = threadIdx.x & 63;
  const int gr = blockIdx.x * 4 + wave;  // 0..16383
  const float* x;
  unsigned char* out;
  int* mslot;
  int row;
  if (gr < N_ROWS) {
    x = ex; out = exn; mslot = rowmax; row = gr;
  } else {
    x = ey; out = eyn; mslot = colmax; row = gr - N_ROWS;
  }
  const float4* xr = (const float4*)(x + (size_t)row * KDIM);
  float4 v[4];
  float ss = 0.f;
#pragma unroll
  for (int j = 0; j < 4; ++j) {
    v[j] = xr[lane + j * 64];  // coalesced
    ss += v[j].x * v[j].x + v[j].y * v[j].y + v[j].z * v[j].z + v[j].w * v[j].w;
  }
#pragma unroll
  for (int off = 32; off > 0; off >>= 1) ss += __shfl_xor(ss, off, 64);
  const float rs = 16.0f * rsqrtf(fmaxf(ss, 1e-24f));  // 2^4 pre-scale
  int* op = (int*)(out + (size_t)row * KDIM);
#pragma unroll
  for (int j = 0; j < 4; ++j) {
    int w = __builtin_amdgcn_cvt_pk_fp8_f32(v[j].x * rs, v[j].y * rs, 0, false);
    w = __builtin_amdgcn_cvt_pk_fp8_f32(v[j].z * rs, v[j].w * rs, w, true);
    op[lane + j * 64] = w;
  }
  if (lane == 0) mslot[row] = (int)0x80000000;  // encoded -inf floor
}

// 128x128 tile GEMM (A @ B^T, row-major K-contiguous e4m3) using MX-scaled
// mfma_scale_f32_32x32x64_f8f6f4, fused with row/col max reduction.
//
// FINAL (r11 champion, re-established after r12-r14 regressions):
//  - __launch_bounds__(256, 4): VGPR 64 arch + 64 acc = 128 -> 4 blocks/CU
//    (the measured optimum; the combined VGPR x LDS occupancy corner).
//  - Pipeline (verified r6+): buffer_load->VGPR->ds_write; the only vmcnt
//    wait is the ds_write data dependence, placed AFTER compute:
//      LOAD(s+1); COMPUTE(buf s&1); WRITE(buf (s+1)&1); barrier
//    (global_load_lds cannot pipeline here: address-blind vmcnt forces a
//    drain before any ds_read — r3/r5 both measured 181 us.)
//  - LDS swizzle (verified r8+): 64-B rows, chunk c of row r at slot
//    c ^ ((r>>1)&3) -> bank-group 4*(r&1)+slot covers all 8 groups x 2
//    lanes per quarter-wave (2-way aliasing is free).
//  - Design-space results: 64x64 wave tile @ BK=64 beats BK=128 (r6 121),
//    128x64 tile (r10 136 / r9 206), A-direct-from-global (r14 150),
//    fused finalize (r13 137 + fence catastrophe r12 355).
__global__ __launch_bounds__(256, 4) void gemm_max_kernel(
    const unsigned char* __restrict__ A, const unsigned char* __restrict__ B,
    int* __restrict__ rowmax, int* __restrict__ colmax) {
  constexpr int TM = 128, BK = 64, K = KDIM;
  constexpr int BUF = TM * BK;                          // 8 KB per buffer
  __shared__ __align__(16) unsigned char sA[2 * BUF];   // 16 KB
  __shared__ __align__(16) unsigned char sB[2 * BUF];   // 16 KB

  const int bm = blockIdx.x, bn = blockIdx.y;
  const int tid = threadIdx.x;
  const int lane = tid & 63, wave = tid >> 6;
  const int wm = wave >> 1, wn = wave & 1;  // 2x2 waves of 64x64
  const int l32 = lane & 31, half = lane >> 5;
  const int fsw = (l32 >> 1) & 3;                 // f(row) = (row>>1)&3
  const int oLo = (((2 * half + 0) ^ fsw) << 4);  // swizzled slot offsets
  const int oHi = (((2 * half + 1) ^ fsw) << 4);

  const char* Ab = (const char*)(A + (size_t)bm * TM * K);
  const char* Bb = (const char*)(B + (size_t)bn * TM * K);

  floatx16 acc[2][2] = {};

  // Staging: wave w stages rows w*32..+31 of each tile per step.
  // Dest (linear lane*16): row r_d = wave*32 + (lane>>2), slot lane&3.
  // Source chunk = (lane&3) ^ f(r_d) = (lane&3) ^ ((lane>>3)&3); the +16-row
  // second write keeps the same offset (f(r+16)==f(r)).
  const int src_c16 = (((lane & 3) ^ ((lane >> 3) & 3)) << 4);
  const char* gA = Ab + (size_t)(wave * 32 + (lane >> 2)) * K + src_c16;
  const char* gB = Bb + (size_t)(wave * 32 + (lane >> 2)) * K + src_c16;
  unsigned char* wA = sA + wave * 2048 + lane * 16;  // linear dest (+buf,+it*1024)
  unsigned char* wB = sB + wave * 2048 + lane * 16;

  intx4 pf[4];  // prefetch regs: 2 A-chunks + 2 B-chunks (16 VGPRs)

#define LOADT(k0)                                            \
  do {                                                       \
    pf[0] = *(const intx4*)(gA + (size_t)(k0));              \
    pf[1] = *(const intx4*)(gA + (size_t)(k0) + 16 * K);     \
    pf[2] = *(const intx4*)(gB + (size_t)(k0));              \
    pf[3] = *(const intx4*)(gB + (size_t)(k0) + 16 * K);     \
  } while (0)

#define WRITET(buf)                                          \
  do {                                                       \
    *(intx4*)(wA + (buf)*BUF) = pf[0];                       \
    *(intx4*)(wA + (buf)*BUF + 1024) = pf[1];                \
    *(intx4*)(wB + (buf)*BUF) = pf[2];                       \
    *(intx4*)(wB + (buf)*BUF + 1024) = pf[3];                \
  } while (0)

#define COMPUTE(cur)                                                        \
  do {                                                                      \
    intx8 aF[2];                                                            \
    _Pragma("unroll") for (int mi = 0; mi < 2; ++mi) {                      \
      const unsigned char* aBase =                                          \
          &sA[(cur)*BUF + (wm * 64 + mi * 32 + l32) * BK];                  \
      const intx4 lo = *(const intx4*)(aBase + oLo);                        \
      const intx4 hi = *(const intx4*)(aBase + oHi);                        \
      aF[mi] = __builtin_shufflevector(lo, hi, 0, 1, 2, 3, 4, 5, 6, 7);     \
    }                                                                       \
    _Pragma("unroll") for (int ni = 0; ni < 2; ++ni) {                      \
      const unsigned char* bBase =                                          \
          &sB[(cur)*BUF + (wn * 64 + ni * 32 + l32) * BK];                  \
      const intx4 lo = *(const intx4*)(bBase + oLo);                        \
      const intx4 hi = *(const intx4*)(bBase + oHi);                        \
      const intx8 bF =                                                      \
          __builtin_shufflevector(lo, hi, 0, 1, 2, 3, 4, 5, 6, 7);          \
      _Pragma("unroll") for (int mi = 0; mi < 2; ++mi)                      \
          acc[mi][ni] = __builtin_amdgcn_mfma_scale_f32_32x32x64_f8f6f4(    \
              aF[mi], bF, acc[mi][ni], 0, 0, 0, SCALE_WORD, 0,              \
              SCALE_WORD);                                                  \
    }                                                                       \
  } while (0)

  LOADT(0);
  WRITET(0);
  __syncthreads();

  // unroll 1: keeps one pf set live (full unroll would hoist all -> spill)
#pragma unroll 1
  for (int step = 0; step < K / BK - 1; ++step) {
    LOADT((step + 1) * BK);   // in flight across the whole compute phase
    COMPUTE(step & 1);
    WRITET((step + 1) & 1);   // vmcnt wait is data-dependent, post-compute
    __syncthreads();
  }
  COMPUTE((K / BK - 1) & 1);

#undef LOADT
#undef WRITET
#undef COMPUTE

  // 32x32 C/D layout (m74/m101, dtype-independent):
  //   col = lane&31, row = (reg&3) + 8*(reg>>2) + 4*(lane>>5), reg in [0,16)
#pragma unroll
  for (int mi = 0; mi < 2; ++mi) {
#pragma unroll
    for (int reg = 0; reg < 16; ++reg) {
      float v = fmaxf(acc[mi][0][reg], acc[mi][1][reg]);
#pragma unroll
      for (int m = 1; m < 32; m <<= 1) v = fmaxf(v, __shfl_xor(v, m, 64));
      if (l32 == 0) {
        const int grow = bm * TM + wm * 64 + mi * 32 +
                         (reg & 3) + 8 * (reg >> 2) + 4 * half;
        atomicMax(&rowmax[grow], fenc(v));
      }
    }
  }
#pragma unroll
  for (int ni = 0; ni < 2; ++ni) {
    float v = -3.402823466e38f;
#pragma unroll
    for (int mi = 0; mi < 2; ++mi)
#pragma unroll
      for (int reg = 0; reg < 16; ++reg) v = fmaxf(v, acc[mi][ni][reg]);
    v = fmaxf(v, __shfl_xor(v, 32, 64));
    if (half == 0) {
      const int gcol = bn * TM + wn * 64 + ni * 32 + l32;
      atomicMax(&colmax[gcol], fenc(v));
    }
  }
}

__global__ __launch_bounds__(1024) void finalize_kernel(
    const int* __restrict__ rowmax, const int* __restrict__ colmax,
    float* __restrict__ out) {
  const int tid = threadIdx.x;
  float s1 = 0.f, s2 = 0.f;
  for (int i = tid; i < N_ROWS; i += 1024) {
    s1 += 1.0f - fdec(rowmax[i]);
    s2 += 1.0f - fdec(colmax[i]);
  }
#pragma unroll
  for (int off = 32; off > 0; off >>= 1) {
    s1 += __shfl_down(s1, off, 64);
    s2 += __shfl_down(s2, off, 64);
  }
  __shared__ float r1[16], r2[16];
  if ((tid & 63) == 0) {
    r1[tid >> 6] = s1;
    r2[tid >> 6] = s2;
  }
  __syncthreads();
  if (tid == 0) {
    const double SIGMA = 0.3;
    const double H_CONST = 0.5 * log(2.0 * 3.14159265358979323846 * SIGMA * SIGMA) + 0.5;
    const float HS = (float)(H_CONST / SIGMA);
    float a1 = 0.f, a2 = 0.f;
#pragma unroll
    for (int w = 0; w < 16; ++w) {
      a1 += r1[w];
      a2 += r2[w];
    }
    out[0] = HS * a1;
    out[1] = HS * a2;
  }
}

extern "C" void kernel_launch(void* const* d_in, const int* in_sizes, int n_in,
                              void* d_out, int out_size, void* d_ws, size_t ws_size,
                              hipStream_t stream) {
  const float* ex = (const float*)d_in[0];
  const float* ey = (const float*)d_in[1];
  float* out = (float*)d_out;
  char* ws = (char*)d_ws;

  unsigned char* exn = (unsigned char*)ws;                                   // 8 MB
  unsigned char* eyn = (unsigned char*)(ws + (size_t)N_ROWS * KDIM);         // 8 MB
  int* rowmax = (int*)(ws + (size_t)N_ROWS * KDIM * 2);                      // 32 KB
  int* colmax = rowmax + N_ROWS;                                             // 32 KB

  normalize_kernel<<<2 * N_ROWS / 4, 256, 0, stream>>>(ex, ey, exn, eyn,
                                                       rowmax, colmax);
  gemm_max_kernel<<<dim3(64, 64), 256, 0, stream>>>(exn, eyn, rowmax, colmax);
  finalize_kernel<<<1, 1024, 0, stream>>>(rowmax, colmax, out);
}